// Round 5
// baseline (1764.138 us; speedup 1.0000x reference)
//
#include <hip/hip_runtime.h>
#include <cmath>

#define HID 51
#define BATCH 256
#define BLK 256      // 4 waves: one heavy wave per layer + 1 output wave
#define NR 204       // 4*HID gate rows per matrix
#define MT 13        // M tiles of 16 covering 208 >= 204 permuted rows

typedef _Float16 v8h   __attribute__((ext_vector_type(8)));
typedef float    f32x4 __attribute__((ext_vector_type(4)));

// One block per batch element (grid = 256 = #CUs). 4 waves, one per SIMD,
// ONE barrier per tick, NO cross-wave gate partials at all.
// Key change vs R4: Wih is FUSED into the heavy wave as extra MFMA K-slabs
//   gates_l(t) = [Whh_l | Wih_l] . [h_l(t-1) ; h_{l-1}(t)]
// so the I-waves, pGI buffers and their LDS hops vanish. Heavy wave l at
// tick tau (local time t = tau - l):
//   1. read h_{l-1}(t) (2 x b128 broadcast, parity (tau-1)&1)    [l>0]
//   2. 26 MFMA: acc[m] += Wih_l . h_{l-1}(t)                     [l>0]
//   3. select acc[cm] via explicit 4-level cndmask tree (lane ell = 16*grp+cm
//      owns unit u = 4*cm+grp; C layout validated in R3/R4: quad = i,f,g,o)
//   4. cell + h_l(t) write (fp16, element cu)
//   5. read back own h_l(t) (2 x b128), 26 MFMA: acc[m] = Whh_l . h_l(t)
//      -> carried in regs across the barrier for tick tau+1
// L0 skips 1-2 (scalar x term folded into the cell via wx4).
// Wave 3: output row Wl . h_2(tau-3) -> obuf ring, 64-wide coalesced flush
// every 64 ticks. waves_per_eu(1,1): 1 wave/SIMD (all we need) -> up to 512
// VGPRs, so HA/IA frags (208) + acc (52) stay resident with no AGPR shuttle.

__device__ __forceinline__ float fsig(float v) {
    return __builtin_amdgcn_rcpf(1.f + __expf(-v));
}
__device__ __forceinline__ float ftanh(float v) {
    const float e = __expf(2.f * v);                 // inf-safe
    return fmaf(-2.f, __builtin_amdgcn_rcpf(e + 1.f), 1.f);
}

__attribute__((amdgpu_waves_per_eu(1, 1)))
__global__ __launch_bounds__(BLK)
void lstm3_kernel(const float* __restrict__ x,
                  const float* __restrict__ Wih1, const float* __restrict__ Whh1,
                  const float* __restrict__ bih1, const float* __restrict__ bhh1,
                  const float* __restrict__ Wih,  const float* __restrict__ Whh,
                  const float* __restrict__ bih,  const float* __restrict__ bhh,
                  const float* __restrict__ Wl,   const float* __restrict__ bl,
                  float* __restrict__ out, int T)
{
    const int b    = blockIdx.x;
    const int tid  = threadIdx.x;
    const int wave = tid >> 6;
    const int lane = tid & 63;
    const int grp  = lane >> 4;                      // 0..3
    const int cm   = lane & 15;                      // tile index / A row

    __shared__ __align__(16) float xbuf[2048];
    __shared__ __align__(16) int   hrow[3][2][32];   // h fp16, 128B rows, parity dbuf
    __shared__ __align__(16) float obuf[128];        // output ring (2 x 64)

    const f32x4 z = {0.f, 0.f, 0.f, 0.f};

    for (int i = tid; i < T; i += BLK) xbuf[i] = x[(size_t)b * T + i];
    if (tid < 192) ((int*)hrow)[tid] = 0;            // both parities, incl. pads

    // ---------------- A fragments (one-time; layout validated R3/R4) ----------
    // A row = lane&15 (= cm), element k = kt*32 + grp*8 + j.
    v8h HA0[MT], HA1[MT], IA0[MT], IA1[MT];
    #pragma unroll
    for (int m = 0; m < MT; ++m) {
        HA0[m] = v8h{0,0,0,0,0,0,0,0}; HA1[m] = HA0[m];
        IA0[m] = HA0[m];               IA1[m] = HA0[m];
    }
    const int akb = grp * 8;
    if (wave < 3) {
        const float* Hs = (wave == 0) ? Whh1 : Whh + (size_t)(wave - 1) * NR * HID;
        #pragma unroll
        for (int m = 0; m < MT; ++m) {
            const int rp = m * 16 + cm;              // permuted row = 4*u + g
            const int uu = rp >> 2, gg = rp & 3;
            #pragma unroll
            for (int kt = 0; kt < 2; ++kt) {
                v8h f;
                #pragma unroll
                for (int j = 0; j < 8; ++j) {
                    const int k = kt * 32 + akb + j;
                    f[j] = (_Float16)((uu < HID && k < HID)
                        ? Hs[(size_t)(gg * HID + uu) * HID + k] : 0.f);
                }
                if (kt == 0) HA0[m] = f; else HA1[m] = f;
            }
        }
        if (wave >= 1) {
            const float* Is = Wih + (size_t)(wave - 1) * NR * HID;
            #pragma unroll
            for (int m = 0; m < MT; ++m) {
                const int rp = m * 16 + cm;
                const int uu = rp >> 2, gg = rp & 3;
                #pragma unroll
                for (int kt = 0; kt < 2; ++kt) {
                    v8h f;
                    #pragma unroll
                    for (int j = 0; j < 8; ++j) {
                        const int k = kt * 32 + akb + j;
                        f[j] = (_Float16)((uu < HID && k < HID)
                            ? Is[(size_t)(gg * HID + uu) * HID + k] : 0.f);
                    }
                    if (kt == 0) IA0[m] = f; else IA1[m] = f;
                }
            }
        }
    } else {                                         // O-wave: row 0 = Wl
        #pragma unroll
        for (int kt = 0; kt < 2; ++kt) {
            v8h f;
            #pragma unroll
            for (int j = 0; j < 8; ++j) {
                const int k = kt * 32 + akb + j;
                f[j] = (_Float16)((cm == 0 && k < HID) ? Wl[k] : 0.f);
            }
            if (kt == 0) HA0[0] = f; else HA1[0] = f;
        }
    }

    // ---------------- cell-lane constants ----------------
    const int  cu      = 4 * cm + grp;               // unit owned by this lane
    const bool is_cell = (wave < 3) && (cm < MT) && (cu < HID);
    const int  cuc     = (cu < HID) ? cu : 0;
    float bias4[4] = {0.f, 0.f, 0.f, 0.f};
    float wx4[4]   = {0.f, 0.f, 0.f, 0.f};
    float c_state  = 0.f, outb = 0.f;
    if (is_cell) {
        #pragma unroll
        for (int k = 0; k < 4; ++k) {
            const int g = k * HID + cuc;
            if (wave == 0) { bias4[k] = bih1[g] + bhh1[g]; wx4[k] = Wih1[g]; }
            else           { const int q = (wave - 1) * NR + g; bias4[k] = bih[q] + bhh[q]; }
        }
    }
    if (wave == 3) outb = bl[0];

    f32x4 acc[MT];                                   // [Whh|Wih].h quads, persistent
    #pragma unroll
    for (int m = 0; m < MT; ++m) acc[m] = z;         // Whh.h(-1) = 0

    const bool b0 = (cm & 1) != 0, b1 = (cm & 2) != 0,
               b2 = (cm & 4) != 0, b3 = (cm & 8) != 0;

    __syncthreads();

    const int TICKS = T + 3;
    for (int tau = 0; tau < TICKS; ++tau) {
        if (wave < 3) {
            const int l  = wave;
            const int tc = tau - l;                  // this layer's local time
            // ---- 1+2: fold Wih . h_{l-1}(t) into carried acc (l>0) ----
            if (l > 0) {
                const char* hbp = (const char*)&hrow[l - 1][(tau - 1) & 1][0];
                const v8h p0 = *(const v8h*)(hbp + (grp << 4));
                const v8h p1 = *(const v8h*)(hbp + 64 + (grp << 4));
                #pragma unroll
                for (int m = 0; m < MT; ++m) {
                    acc[m] = __builtin_amdgcn_mfma_f32_16x16x32_f16(IA0[m], p0, acc[m], 0, 0, 0);
                    acc[m] = __builtin_amdgcn_mfma_f32_16x16x32_f16(IA1[m], p1, acc[m], 0, 0, 0);
                }
            }
            // ---- 3: select acc[cm] (4-level tree, compile-time indices) ----
            const f32x4 s0 = b0 ? acc[1]  : acc[0];
            const f32x4 s1 = b0 ? acc[3]  : acc[2];
            const f32x4 s2 = b0 ? acc[5]  : acc[4];
            const f32x4 s3 = b0 ? acc[7]  : acc[6];
            const f32x4 s4 = b0 ? acc[9]  : acc[8];
            const f32x4 s5 = b0 ? acc[11] : acc[10];
            const f32x4 s6 = acc[12];
            const f32x4 u0 = b1 ? s1 : s0;
            const f32x4 u1 = b1 ? s3 : s2;
            const f32x4 u2 = b1 ? s5 : s4;
            const f32x4 v0 = b2 ? u1 : u0;
            const f32x4 wh = b3 ? (b2 ? s6 : u2) : v0;
            // ---- 4: cell + h write ----
            if (is_cell && (unsigned)tc < (unsigned)T) {
                float gi  = bias4[0] + wh[0];
                float gf  = bias4[1] + wh[1];
                float gg_ = bias4[2] + wh[2];
                float go  = bias4[3] + wh[3];
                if (l == 0) {
                    const float xv = xbuf[tc];       // wave-uniform broadcast
                    gi  = fmaf(wx4[0], xv, gi);
                    gf  = fmaf(wx4[1], xv, gf);
                    gg_ = fmaf(wx4[2], xv, gg_);
                    go  = fmaf(wx4[3], xv, go);
                }
                const float c = fmaf(fsig(gf), c_state, fsig(gi) * ftanh(gg_));
                c_state = c;
                ((_Float16*)&hrow[l][tau & 1][0])[cuc] = (_Float16)(fsig(go) * ftanh(c));
            }
            // ---- 5+6: acc = Whh . h_l(t) for next tick ----
            const char* hbc = (const char*)&hrow[l][tau & 1][0];
            const v8h c0 = *(const v8h*)(hbc + (grp << 4));
            const v8h c1 = *(const v8h*)(hbc + 64 + (grp << 4));
            #pragma unroll
            for (int m = 0; m < MT; ++m) {
                acc[m] = __builtin_amdgcn_mfma_f32_16x16x32_f16(HA0[m], c0, z, 0, 0, 0);
                acc[m] = __builtin_amdgcn_mfma_f32_16x16x32_f16(HA1[m], c1, acc[m], 0, 0, 0);
            }
        } else {
            // ---- O-wave: Wl . h_2(tau-3) + coalesced flush ----
            const char* hb = (const char*)&hrow[2][(tau - 1) & 1][0];
            const v8h f0 = *(const v8h*)(hb + (grp << 4));
            const v8h f1 = *(const v8h*)(hb + 64 + (grp << 4));
            f32x4 a = __builtin_amdgcn_mfma_f32_16x16x32_f16(HA0[0], f0, z, 0, 0, 0);
            a = __builtin_amdgcn_mfma_f32_16x16x32_f16(HA1[0], f1, a, 0, 0, 0);
            const int to = tau - 3;
            if (lane == 0 && (unsigned)to < (unsigned)T)
                obuf[to & 127] = a[0] + outb;        // C row0 col0 lives in lane 0
            if ((tau & 63) == 2 && tau >= 66) {      // block [t0, t0+63] complete
                const int t0 = tau - 66;             // multiple of 64
                out[(size_t)b * T + t0 + lane] = obuf[(t0 & 64) + lane];
            }
        }
        __syncthreads();                             // the ONLY barrier per tick
    }
}

extern "C" void kernel_launch(void* const* d_in, const int* in_sizes, int n_in,
                              void* d_out, int out_size, void* d_ws, size_t ws_size,
                              hipStream_t stream) {
    const float* x    = (const float*)d_in[0];
    const float* Wih1 = (const float*)d_in[1];
    const float* Whh1 = (const float*)d_in[2];
    const float* bih1 = (const float*)d_in[3];
    const float* bhh1 = (const float*)d_in[4];
    const float* Wih  = (const float*)d_in[5];
    const float* Whh  = (const float*)d_in[6];
    const float* bih  = (const float*)d_in[7];
    const float* bhh  = (const float*)d_in[8];
    const float* Wl   = (const float*)d_in[9];
    const float* bl   = (const float*)d_in[10];
    float* out = (float*)d_out;

    const int T = in_sizes[0] / BATCH;   // 2048 (flush assumes T % 64 == 0)
    lstm3_kernel<<<BATCH, BLK, 0, stream>>>(x, Wih1, Whh1, bih1, bhh1,
                                            Wih, Whh, bih, bhh, Wl, bl, out, T);
}

// Round 6
// 1419.410 us; speedup vs baseline: 1.2429x; 1.2429x over previous
//
#include <hip/hip_runtime.h>
#include <cmath>

#define HID 51
#define BATCH 256
#define BLK 512      // 8 waves
#define NR 204       // 4*HID gate rows per matrix

typedef _Float16 half2_t __attribute__((ext_vector_type(2)));

// One block per batch element (grid = 256 = #CUs). R1's PROVEN 2-phase /
// 2-barrier schedule (cells consume gate partials written the same tick,
// phase A reads h written last tick's phase B; skew 1 tick per layer),
// with three fixes:
//  - h broadcast via 7 int4 LDS loads unpacked to SCALAR ints (SROA-safe;
//    R2's float4-array + pointer-cast variant spilled to scratch) -- no
//    readlanes (R1 spent ~26 v_readlane per row on this).
//  - TWO dot rows per lane, 8 waves. Pairs share the same h source row
//    (verified same-value: m0+m2 read h0(tau-1), m1+m4 read h1(tau-2),
//    m3+m3 read h2(tau-3), out reads h2(tau-3)):
//      tid [0,204):   rows (m0: L0 Whh, g=tid, lp=0) + (m2: L1 Wih, g=tid, lp=1)
//      tid [204,408): rows (m1: L1 Whh, lp=1)        + (m4: L2 Wih, lp=2)
//      tid [408,510): rows (m3: L2 Whh, g=2i, lp=2)  + (m3, g=2i+1, lp=2)
//      tid 510:       output row Wl.h2 + bl -> obuf   (lp=3)
//  - phase-B rebalanced: cell L0 -> wave 3 (SIMD3), L1 -> wave 5 (SIMD1),
//    L2 -> wave 6 (SIMD2), obuf flush -> wave 4 (SIMD0). Each SIMD carries
//    at most one phase-B role (R1 piled all cells on SIMDs 0-2).
// Dot issue per SIMD is invariant (~104 dot2-insts/SIMD/tick); the wins are
// readlane removal, 8-wave (cheaper) barriers, and SIMD balance.

__device__ __forceinline__ float fsig(float v) {
    return __builtin_amdgcn_rcpf(1.f + __expf(-v));
}
__device__ __forceinline__ float ftanh(float v) {
    const float e = __expf(2.f * v);                 // inf-safe
    return fmaf(-2.f, __builtin_amdgcn_rcpf(e + 1.f), 1.f);
}
__device__ __forceinline__ half2_t h2bits(int b) {
    union { int i; half2_t h; } u; u.i = b; return u.h;
}

__attribute__((amdgpu_waves_per_eu(2, 2)))
__global__ __launch_bounds__(BLK)
void lstm3_kernel(const float* __restrict__ x,
                  const float* __restrict__ Wih1, const float* __restrict__ Whh1,
                  const float* __restrict__ bih1, const float* __restrict__ bhh1,
                  const float* __restrict__ Wih,  const float* __restrict__ Whh,
                  const float* __restrict__ bih,  const float* __restrict__ bhh,
                  const float* __restrict__ Wl,   const float* __restrict__ bl,
                  float* __restrict__ out, int T)
{
    const int b    = blockIdx.x;
    const int tid  = threadIdx.x;
    const int wave = tid >> 6;
    const int lane = tid & 63;

    __shared__ __align__(16) float xbuf[2048];
    __shared__ __align__(16) int   hrow[3][32];      // h fp16 pairs, 128B rows
    __shared__ __align__(16) float gP[5][NR];        // gate partials [gate*51+u]
    __shared__ __align__(16) float obuf[128];        // output ring (2 x 64)

    for (int i = tid; i < T; i += BLK) xbuf[i] = x[(size_t)b * T + i];
    if (tid < 96) ((int*)hrow)[tid] = 0;             // h = 0 incl. pads

    // ---------------- phase-A roles: two dot rows per lane ----------------
    int srcrow = 2, mA = -1, gA = 0, lpA = 0, mB = -1, gB = 0, lpB = 0;
    bool isOut = false;
    if (tid < 204)       { srcrow = 0; mA = 0; gA = tid;       lpA = 0;
                                       mB = 2; gB = tid;       lpB = 1; }
    else if (tid < 408)  { srcrow = 1; mA = 1; gA = tid - 204; lpA = 1;
                                       mB = 4; gB = tid - 204; lpB = 2; }
    else if (tid < 510)  { const int i2 = tid - 408;
                           srcrow = 2; mA = 3; gA = 2 * i2;     lpA = 2;
                                       mB = 3; gB = 2 * i2 + 1; lpB = 2; }
    else if (tid == 510) { srcrow = 2; isOut = true; lpA = 3; }

    const float* wsA = nullptr;
    const float* wsB = nullptr;
    if      (mA == 0) wsA = Whh1 + (size_t)gA * HID;
    else if (mA == 1) wsA = Whh  + (size_t)gA * HID;
    else if (mA == 3) wsA = Whh  + (size_t)(NR + gA) * HID;
    if (isOut)        wsA = Wl;
    if      (mB == 2) wsB = Wih  + (size_t)gB * HID;
    else if (mB == 4) wsB = Wih  + (size_t)(NR + gB) * HID;
    else if (mB == 3) wsB = Whh  + (size_t)(NR + gB) * HID;

    half2_t w2a[26], w2b[26];
    #pragma unroll
    for (int j = 0; j < 26; ++j) {
        w2a[j] = half2_t{(_Float16)0.f, (_Float16)0.f};
        w2b[j] = w2a[j];
    }
    if (wsA) {
        #pragma unroll
        for (int j = 0; j < 25; ++j)
            w2a[j] = half2_t{(_Float16)wsA[2*j], (_Float16)wsA[2*j+1]};
        w2a[25] = half2_t{(_Float16)wsA[50], (_Float16)0.f};
    }
    if (wsB) {
        #pragma unroll
        for (int j = 0; j < 25; ++j)
            w2b[j] = half2_t{(_Float16)wsB[2*j], (_Float16)wsB[2*j+1]};
        w2b[25] = half2_t{(_Float16)wsB[50], (_Float16)0.f};
    }
    const float obias = isOut ? bl[0] : 0.f;
    float* dstA = (mA >= 0) ? &gP[mA][gA] : nullptr;
    float* dstB = (mB >= 0) ? &gP[mB][gB] : nullptr;

    // ---------------- phase-B roles ----------------
    // cell L0 -> wave 3 (SIMD3), L1 -> wave 5 (SIMD1), L2 -> wave 6 (SIMD2)
    const int cwl = (wave == 3) ? 0 : (wave == 5) ? 1 : (wave == 6) ? 2 : -1;
    const bool is_cell = (cwl >= 0) && (lane < HID);
    float bias4[4] = {0.f, 0.f, 0.f, 0.f};
    float wx4[4]   = {0.f, 0.f, 0.f, 0.f};
    float c_state  = 0.f;
    if (is_cell) {
        #pragma unroll
        for (int k = 0; k < 4; ++k) {
            const int g = k * HID + lane;
            if (cwl == 0) { bias4[k] = bih1[g] + bhh1[g]; wx4[k] = Wih1[g]; }
            else          { const int q = (cwl - 1) * NR + g; bias4[k] = bih[q] + bhh[q]; }
        }
    }

    __syncthreads();

    const int TICKS = T + 3;
    for (int tau = 0; tau < TICKS; ++tau) {
        // ---------------- phase A: 2 dot rows per lane ----------------
        {
            int hw[28];                              // scalar unpack: SROA-safe
            #pragma unroll
            for (int k = 0; k < 7; ++k) {
                const int4 q = ((const int4*)&hrow[srcrow][0])[k];  // broadcast
                hw[4*k+0] = q.x; hw[4*k+1] = q.y; hw[4*k+2] = q.z; hw[4*k+3] = q.w;
            }
            float aA0 = obias, aA1 = 0.f, aB0 = 0.f, aB1 = 0.f;
            #pragma unroll
            for (int j = 0; j < 26; ++j) {
                const half2_t hj = h2bits(hw[j]);
                if (j & 1) {
                    aA1 = __builtin_amdgcn_fdot2(w2a[j], hj, aA1, false);
                    aB1 = __builtin_amdgcn_fdot2(w2b[j], hj, aB1, false);
                } else {
                    aA0 = __builtin_amdgcn_fdot2(w2a[j], hj, aA0, false);
                    aB0 = __builtin_amdgcn_fdot2(w2b[j], hj, aB0, false);
                }
            }
            const int tA = tau - lpA, tB = tau - lpB;
            if ((unsigned)tA < (unsigned)T) {
                if (dstA)       *dstA = aA0 + aA1;
                else if (isOut) obuf[tA & 127] = aA0 + aA1;
            }
            if (dstB && (unsigned)tB < (unsigned)T) *dstB = aB0 + aB1;
        }
        __syncthreads();
        // ---------------- phase B: cells (one wave per SIMD) + flush ----------------
        if (is_cell) {
            const int t = tau - cwl;
            if ((unsigned)t < (unsigned)T) {
                const float* pW = gP[cwl == 0 ? 0 : (cwl == 1 ? 1 : 3)];
                float gi  = bias4[0] + pW[lane];
                float gf  = bias4[1] + pW[HID + lane];
                float gg_ = bias4[2] + pW[2 * HID + lane];
                float go  = bias4[3] + pW[3 * HID + lane];
                if (cwl == 0) {
                    const float xv = xbuf[t];        // uniform broadcast
                    gi  = fmaf(wx4[0], xv, gi);
                    gf  = fmaf(wx4[1], xv, gf);
                    gg_ = fmaf(wx4[2], xv, gg_);
                    go  = fmaf(wx4[3], xv, go);
                } else {
                    const float* pI = gP[cwl == 1 ? 2 : 4];
                    gi  += pI[lane];
                    gf  += pI[HID + lane];
                    gg_ += pI[2 * HID + lane];
                    go  += pI[3 * HID + lane];
                }
                const float c = fmaf(fsig(gf), c_state, fsig(gi) * ftanh(gg_));
                c_state = c;
                ((_Float16*)&hrow[cwl][0])[lane] = (_Float16)(fsig(go) * ftanh(c));
            }
        } else if (wave == 4 && (tau & 63) == 2 && tau >= 66) {
            // out(t) lands in obuf at tick t+3 (phase A); block complete here
            const int t0 = tau - 66;                 // multiple of 64
            out[(size_t)b * T + t0 + lane] = obuf[(t0 & 64) + lane];
        }
        __syncthreads();
    }
}

extern "C" void kernel_launch(void* const* d_in, const int* in_sizes, int n_in,
                              void* d_out, int out_size, void* d_ws, size_t ws_size,
                              hipStream_t stream) {
    const float* x    = (const float*)d_in[0];
    const float* Wih1 = (const float*)d_in[1];
    const float* Whh1 = (const float*)d_in[2];
    const float* bih1 = (const float*)d_in[3];
    const float* bhh1 = (const float*)d_in[4];
    const float* Wih  = (const float*)d_in[5];
    const float* Whh  = (const float*)d_in[6];
    const float* bih  = (const float*)d_in[7];
    const float* bhh  = (const float*)d_in[8];
    const float* Wl   = (const float*)d_in[9];
    const float* bl   = (const float*)d_in[10];
    float* out = (float*)d_out;

    const int T = in_sizes[0] / BATCH;   // 2048 (flush assumes T % 64 == 0)
    lstm3_kernel<<<BATCH, BLK, 0, stream>>>(x, Wih1, Whh1, bih1, bhh1,
                                            Wih, Whh, bih, bhh, Wl, bl, out, T);
}

// Round 7
// 1410.675 us; speedup vs baseline: 1.2506x; 1.0062x over previous
//
#include <hip/hip_runtime.h>
#include <cmath>

#define HID 51
#define BATCH 256
#define BLK 1024     // 16 waves
#define NR 204       // 4*HID gate rows per matrix

typedef _Float16 half2_t __attribute__((ext_vector_type(2)));

// One block per batch element (grid = 256 = #CUs). R1's proven 16-wave /
// 2-barrier schedule with R6's proven codegen fixes:
//  - h broadcast via 7 uniform-address int4 LDS loads unpacked to SCALAR
//    ints (no v_readlane: R1 spent ~26 readlane/row = ~195 cy/SIMD/tick).
//  - gP stored as GATE QUADS: row g writes gP[role][(g%51)*4 + g/51], so a
//    cell lane reads its (i,f,g,o) as ONE b128 per partial set (R1 did 8
//    strided scalar reads).
//  - cell waves layer-aligned: wave 0 -> L0 (SIMD0), wave 1 -> L1 (SIMD1),
//    wave 2 -> L2 (SIMD2), flush wave 3 (SIMD3). Wave-uniform branches.
// Phase-A role map is R1's (wave<15: role=wave/3, g=(wave%3)*64+lane;
// wave 15: 5x12 leftover gates + output lane). Roles (t = tau - lp):
//   0: L0 full gate  bias+wx*x[t] + Whh1 g . h0   (lp 0)
//   1: L1 Wih g . h0 (carries bias)               (lp 1)
//   2: L1 Whh g . h1                              (lp 1)
//   3: L2 Wih g . h1 (carries bias)               (lp 2)
//   4: L2 Whh g . h2                              (lp 2)
//   5: output Wl . h2 + bl -> obuf ring           (lp 3)
// Cell l at tick tau computes t = tau-l from this tick's partials (barrier
// 1 between), writes h_l as fp16 (barrier 2 before next tick's reads).
// Output ring flushed 64-wide by wave 3 every 64 ticks.

__device__ __forceinline__ float fsig(float v) {
    return __builtin_amdgcn_rcpf(1.f + __expf(-v));
}
__device__ __forceinline__ float ftanh(float v) {
    const float e = __expf(2.f * v);                 // inf-safe
    return fmaf(-2.f, __builtin_amdgcn_rcpf(e + 1.f), 1.f);
}
__device__ __forceinline__ half2_t h2bits(int b) {
    union { int i; half2_t h; } u; u.i = b; return u.h;
}

__attribute__((amdgpu_waves_per_eu(4, 4)))
__global__ __launch_bounds__(BLK)
void lstm3_kernel(const float* __restrict__ x,
                  const float* __restrict__ Wih1, const float* __restrict__ Whh1,
                  const float* __restrict__ bih1, const float* __restrict__ bhh1,
                  const float* __restrict__ Wih,  const float* __restrict__ Whh,
                  const float* __restrict__ bih,  const float* __restrict__ bhh,
                  const float* __restrict__ Wl,   const float* __restrict__ bl,
                  float* __restrict__ out, int T)
{
    const int b    = blockIdx.x;
    const int tid  = threadIdx.x;
    const int wave = tid >> 6;
    const int lane = tid & 63;

    __shared__ __align__(16) float xbuf[2048];
    __shared__ __align__(16) int   hrow[3][32];      // h fp16 pairs, 128B rows
    __shared__ __align__(16) float gP[5][NR];        // partials as quads [u*4+gate]
    __shared__ __align__(16) float obuf[128];        // output ring (2 x 64)

    for (int i = tid; i < T; i += BLK) xbuf[i] = x[(size_t)b * T + i];
    if (tid < 96) ((int*)hrow)[tid] = 0;             // h = 0 incl. pads

    // ---------------- phase-A role assignment (R1's map) ----------------
    int role = -1, g = 0;
    if (wave < 15)       { role = wave / 3; g = (wave % 3) * 64 + lane; }
    else if (lane < 60)  { role = lane / 12; g = 192 + lane % 12; }
    else if (lane == 60) { role = 5; }

    const float* rowp = nullptr;
    float wx = 0.f, bias = 0.f;
    int srcrow = 0, lp = 1 << 20;
    bool isOut = false;
    if (role == 0) {
        wx   = Wih1[g];
        bias = bih1[g] + bhh1[g];
        rowp = Whh1 + (size_t)g * HID;
        srcrow = 0; lp = 0;
    } else if (role == 1) {
        bias = bih[g] + bhh[g];
        rowp = Wih + (size_t)g * HID;
        srcrow = 0; lp = 1;
    } else if (role == 2) {
        rowp = Whh + (size_t)g * HID;
        srcrow = 1; lp = 1;
    } else if (role == 3) {
        bias = bih[NR + g] + bhh[NR + g];
        rowp = Wih + (size_t)(NR + g) * HID;
        srcrow = 1; lp = 2;
    } else if (role == 4) {
        rowp = Whh + (size_t)(NR + g) * HID;
        srcrow = 2; lp = 2;
    } else if (role == 5) {
        bias = bl[0];
        rowp = Wl;
        srcrow = 2; lp = 3; isOut = true;
    }

    float* dst = nullptr;
    if (role >= 0 && role < 5) {
        const int d = (g * 1286) >> 16;              // g / 51  (valid g <= 203)
        const int u = g - 51 * d;                    // g % 51
        dst = &gP[role][u * 4 + d];                  // quad layout
    }
    const int4* hp = (const int4*)&hrow[srcrow][0];

    half2_t w2[26];
    #pragma unroll
    for (int j = 0; j < 26; ++j) w2[j] = half2_t{(_Float16)0.f, (_Float16)0.f};
    if (rowp) {
        #pragma unroll
        for (int j = 0; j < 25; ++j)
            w2[j] = half2_t{(_Float16)rowp[2*j], (_Float16)rowp[2*j+1]};
        w2[25] = half2_t{(_Float16)rowp[50], (_Float16)0.f};
    }

    // ---------------- phase-B role (layer-aligned cell waves) ----------------
    const bool is_cell = (wave < 3) && (lane < HID);
    float c_state = 0.f;

    __syncthreads();

    const int TICKS = T + 3;
    for (int tau = 0; tau < TICKS; ++tau) {
        // ---------------- phase A: gate dot rows ----------------
        if (role >= 0) {
            const int  t    = tau - lp;              // wave-uniform for wave<15
            const bool pred = (unsigned)t < (unsigned)T;
            int hw[28];                              // scalar unpack: SROA-safe
            #pragma unroll
            for (int k = 0; k < 7; ++k) {
                const int4 q = hp[k];                // broadcast (uniform addr)
                hw[4*k+0] = q.x; hw[4*k+1] = q.y; hw[4*k+2] = q.z; hw[4*k+3] = q.w;
            }
            float acc0 = fmaf(wx, xbuf[pred ? t : 0], bias);  // wx=0 unless role 0
            float acc1 = 0.f;
            #pragma unroll
            for (int j = 0; j < 26; ++j) {
                const half2_t hj = h2bits(hw[j]);
                if (j & 1) acc1 = __builtin_amdgcn_fdot2(w2[j], hj, acc1, false);
                else       acc0 = __builtin_amdgcn_fdot2(w2[j], hj, acc0, false);
            }
            if (pred) {
                if (isOut) obuf[t & 127] = acc0 + acc1;
                else       *dst = acc0 + acc1;
            }
        }
        __syncthreads();
        // ---------------- phase B: cells (1 wave/SIMD) + flush ----------------
        if (is_cell) {
            const int t = tau - wave;                // wave-uniform
            if ((unsigned)t < (unsigned)T) {
                const float4 qa = *(const float4*)&gP[wave == 0 ? 0 : (wave == 1 ? 1 : 3)][lane * 4];
                float gi = qa.x, gf = qa.y, gg_ = qa.z, go = qa.w;
                if (wave > 0) {
                    const float4 qb = *(const float4*)&gP[wave == 1 ? 2 : 4][lane * 4];
                    gi += qb.x; gf += qb.y; gg_ += qb.z; go += qb.w;
                }
                const float c = fmaf(fsig(gf), c_state, fsig(gi) * ftanh(gg_));
                c_state = c;
                ((_Float16*)&hrow[wave][0])[lane] = (_Float16)(fsig(go) * ftanh(c));
            }
        } else if (wave == 3 && (tau & 63) == 2 && tau >= 66) {
            // out(t) lands in obuf at tick t+3 (phase A); block complete here
            const int t0 = tau - 66;                 // multiple of 64
            out[(size_t)b * T + t0 + lane] = obuf[(t0 & 64) + lane];
        }
        __syncthreads();
    }
}

extern "C" void kernel_launch(void* const* d_in, const int* in_sizes, int n_in,
                              void* d_out, int out_size, void* d_ws, size_t ws_size,
                              hipStream_t stream) {
    const float* x    = (const float*)d_in[0];
    const float* Wih1 = (const float*)d_in[1];
    const float* Whh1 = (const float*)d_in[2];
    const float* bih1 = (const float*)d_in[3];
    const float* bhh1 = (const float*)d_in[4];
    const float* Wih  = (const float*)d_in[5];
    const float* Whh  = (const float*)d_in[6];
    const float* bih  = (const float*)d_in[7];
    const float* bhh  = (const float*)d_in[8];
    const float* Wl   = (const float*)d_in[9];
    const float* bl   = (const float*)d_in[10];
    float* out = (float*)d_out;

    const int T = in_sizes[0] / BATCH;   // 2048 (flush assumes T % 64 == 0)
    lstm3_kernel<<<BATCH, BLK, 0, stream>>>(x, Wih1, Whh1, bih1, bhh1,
                                            Wih, Whh, bih, bhh, Wl, bl, out, T);
}